// Round 7
// baseline (402.801 us; speedup 1.0000x reference)
//
#include <hip/hip_runtime.h>
#include <math.h>

#define W    3072
#define HH   3072
#define HOUT 3060       // HH - 12 (valid conv output for 13x13 kernel)
#define TW   64         // output cols per block
#define TH   44         // output rows per block (4 waves x 11 rows)
#define RW   11         // rows per wave
#define XR   56         // xt rows = TH + 12
#define XTS  76         // xt col stride
#define VTS  77         // vt col stride (odd -> scalar reads/writes conflict-free)
#define VTW  (RW*VTS)   // per-wave vt words = 847
#define GX   48
#define GY   70         // 70*44 = 3080 >= 3072 (masked)
#define GZ   2
#define NBLK (GX*GY*GZ)
#define NTHR (NBLK*256)
#define NSLOT 64        // accumulator slots, each (slot,j) on its own 64B line
#define NSTG ((XR*19+255)/256)   // staging iterations per thread = 5

struct HessTaps { float a[13]; float bb[13]; float m[13]; float n[13]; };

// ---- module-global accumulator state: ZERO-INITIALIZED at module load, and
// SELF-RESETTING (the last block re-zeroes everything it consumed), so no
// hipMemsetAsync dispatch is needed. Dispatch marginal cost in this harness
// is ~24us (R0/R1 5-dispatch gap ~200us vs R2-R6 3-dispatch gap ~155us), so
// collapsing memset+finalize into the main kernel saves ~48us of fixed cost.
// Slot-spreading across 64 lines stays: atomics to one 64B line serialize at
// ~13ns (the session's rounds 0-4 hidden serializer; fixed in round 5).
__device__ double       g_slots[NSLOT * 32];   // (slot,j) at byte slot*256+j*64
__device__ unsigned int g_ticket = 0;

// ---- Hessian + TV + folded gf/mse, both images via gridDim.z ---------------
// 64x44 output tile, 4 waves x 11 rows, wave-local V->H (vt wave-private),
// scalar f32 FMAs (v_pk_fma_f32 is half-rate on gfx950: fp32 peak == scalar
// FMA rate, verified rounds 1-2). Conv body identical to round 6 (117us,
// VALUBusy 72%, occupancy 49% @ 5 blocks/CU):
//  * TH 44 -> LDS 30628 -> 5 blocks/CU (occupancy ceiling 62.5%).
//  * T window preloaded into 5 static float4 regs BEFORE barrier 1: the
//    d-update phase is pure LDS/VALU (no global-load bubble).
//  * gf/mse global loads issued before barrier 1, consumed at the end.
// Round-7: single-dispatch everything -- fused end reduction (1 barrier),
// ticketed last-block finalize (atomicExch = coherent read + re-zero).
__global__ __launch_bounds__(256, 5) void hess_kernel(const float* __restrict__ Gnn,
                                                      const float* __restrict__ Lr,
                                                      const float* __restrict__ T,
                                                      const float* __restrict__ Xr,
                                                      const float* __restrict__ St,
                                                      const float* __restrict__ Mp,
                                                      float* __restrict__ out,
                                                      HessTaps tp) {
  __shared__ float xt[XR * XTS];
  __shared__ float vt[4 * VTW];
  __shared__ float red[4][3];
  __shared__ unsigned int lastflag;
  const float* img = (blockIdx.z == 0) ? Gnn : Lr;
  int oy = blockIdx.y * TH, ox = blockIdx.x * TW;
  int t = threadIdx.x;
  int wv = t >> 6, ln = t & 63;    // wave id 0..3, lane 0..63
  int r0 = wv * RW;

  // load xt (56 rows x 76 cols) as aligned float4 with edge masking
  for (int idx = t; idx < XR * 19; idx += 256) {
    int r = idx / 19, g = idx - r * 19;
    int gr = oy + r, gc = ox + 4 * g;
    float4 v = {0.f, 0.f, 0.f, 0.f};
    if (gr < HH) {
      const float* p = &img[(size_t)gr * W + gc];
      if (gc + 3 < W) v = *(const float4*)p;
      else {
        if (gc < W)     v.x = p[0];
        if (gc + 1 < W) v.y = p[1];
        if (gc + 2 < W) v.z = p[2];
      }
    }
    *(float4*)&xt[r * XTS + 4 * g] = v;
  }

  // ---- preload the T window for the d-update (static 5x float4, masked);
  // latency hides under term-1 compute instead of stalling at barrier 2.
  float4 tr4[NSTG];
  #pragma unroll
  for (int k = 0; k < NSTG; ++k) {
    int idx = t + 256 * k;
    float4 v = {0.f, 0.f, 0.f, 0.f};
    if (idx < XR * 19) {
      int r = idx / 19, g = idx - r * 19;
      int gr = oy + r, gc = ox + 4 * g;
      if (gr < HH) {
        const float* p = &T[(size_t)gr * W + gc];
        if (gc + 3 < W) v = *(const float4*)p;
        else {
          if (gc < W)     v.x = p[0];
          if (gc + 1 < W) v.y = p[1];
          if (gc + 2 < W) v.z = p[2];
        }
      }
    }
    tr4[k] = v;
  }

  // ---- issue gf/mse global loads now; latency hides under the whole conv
  int bid = (blockIdx.z * GY + blockIdx.y) * GX + blockIdx.x;
  int i0 = bid * 256 + t;
  int i1 = i0 + NTHR;
  const int n4 = (W * HH) / 4;
  float4 ga0 = ((const float4*)Xr)[i0];    // i0 < NTHR <= n4 always
  float4 gb0 = ((const float4*)St)[i0];
  float4 ga1 = {0.f, 0.f, 0.f, 0.f}, gb1 = ga1;
  bool has1 = (i1 < n4);
  if (has1) { ga1 = ((const float4*)Xr)[i1]; gb1 = ((const float4*)St)[i1]; }
  float mT = 0.f, mG = 0.f, mM = 0.f;
  bool hasm = (i0 < 384 * 384);
  if (hasm) {
    int si = i0 / 384, sj = i0 - si * 384;
    int id = si * 8 * W + sj * 8;
    mT = T[id]; mG = Gnn[id]; mM = Mp[id];
  }
  __builtin_amdgcn_sched_barrier(0);

  __syncthreads();     // barrier 1: xt staged

  float tvl = 0.f;   // TV accumulator
  float hl  = 0.f;   // Hessian accumulator

  // TV Dx term on x: |x(r,c) - x(r,c+1)|  (lanes contiguous -> free)
  {
    int gc = ox + ln;
    if (gc < W - 1) {
      #pragma unroll
      for (int i = 0; i < RW; ++i) {
        int r = r0 + i;
        if (oy + r < HH)
          tvl += fabsf(xt[r * XTS + ln] - xt[r * XTS + ln + 1]);
      }
    }
  }

  // ---- V pass: main 64 cols (all lanes) + dense halo (12x11=132 outputs,
  // <=3 per lane). Per-output tap order u-ascending -> bitwise identical.
  #define VPASS(TAP)                                                        \
    {                                                                       \
      /* main: lane = col ln; 11 sliding accumulators over 23-row window */ \
      float oA[RW];                                                         \
      _Pragma("unroll")                                                     \
      for (int i = 0; i < RW; ++i) oA[i] = 0.f;                             \
      _Pragma("unroll")                                                     \
      for (int u = 0; u < RW + 12; ++u) {                                   \
        float xA = xt[(r0 + u) * XTS + ln];                                 \
        _Pragma("unroll")                                                   \
        for (int i = 0; i < RW; ++i) {                                      \
          int kk = u - i;                                                   \
          if (kk >= 0 && kk <= 12) oA[i] = fmaf((TAP)[kk], xA, oA[i]);      \
        }                                                                   \
      }                                                                     \
      float* vw = &vt[wv * VTW + ln];                                       \
      _Pragma("unroll")                                                     \
      for (int i = 0; i < RW; ++i) vw[i * VTS] = oA[i];                     \
      /* halo: 12 cols x 11 rows = 132 outputs, <=3 per lane */             \
      _Pragma("unroll")                                                     \
      for (int k = 0; k < 3; ++k) {                                         \
        int o = ln + 64 * k;                                                \
        if (o < 12 * RW) {                                                  \
          int row = o / 12, hc = o - row * 12;                              \
          const float* xp = &xt[(r0 + row) * XTS + 64 + hc];                \
          float s = 0.f;                                                    \
          _Pragma("unroll")                                                 \
          for (int u = 0; u < 13; ++u) s = fmaf((TAP)[u], xp[u * XTS], s);  \
          vt[wv * VTW + row * VTS + 64 + hc] = s;                           \
        }                                                                   \
      }                                                                     \
    }

  // ---- H pass: scalar sliding reads of the SAME wave's vt rows (stride 77
  // -> <=2 lanes/bank); 16 register accumulators, tap order j-ascending.
  #define HSECOND(TAP, WGT)                                                 \
    {                                                                       \
      int r14 = ln & 15, cg = ln >> 4;                                      \
      if (r14 < RW) {                                                       \
        const float* vrow = &vt[wv * VTW + r14 * VTS + cg * 16];            \
        float o_[16];                                                       \
        _Pragma("unroll")                                                   \
        for (int jj = 0; jj < 16; ++jj) o_[jj] = 0.f;                       \
        _Pragma("unroll")                                                   \
        for (int j = 0; j < 28; ++j) {                                      \
          float v = vrow[j];                                                \
          _Pragma("unroll")                                                 \
          for (int jj = 0; jj < 16; ++jj) {                                 \
            int kk = j - jj;                                                \
            if (kk >= 0 && kk <= 12) o_[jj] = fmaf((TAP)[kk], v, o_[jj]);   \
          }                                                                 \
        }                                                                   \
        int gr = oy + r0 + r14;                                             \
        int gc0 = ox + cg * 16;                                             \
        float wr = (gr < HOUT) ? (WGT) : 0.f;                               \
        _Pragma("unroll")                                                   \
        for (int jj = 0; jj < 16; ++jj) {                                   \
          float m_ = (gc0 + jj < HOUT) ? wr : 0.f;                          \
          hl = fmaf(m_, fabsf(o_[jj]), hl);                                 \
        }                                                                   \
      }                                                                     \
    }

  // term 1: conv(x, Gxx) = vert bb, horiz a   (vt is wave-private: no barrier)
  VPASS(tp.bb);
  HSECOND(tp.a, 1.0f);

  // d = x - target (in place), using the preloaded T registers: pure
  // LDS/VALU between the barriers -- no global-load bubble.
  __syncthreads();     // barrier 2
  #pragma unroll
  for (int k = 0; k < NSTG; ++k) {
    int idx = t + 256 * k;
    if (idx < XR * 19) {
      int r = idx / 19, g = idx - r * 19;
      float4 cur = *(float4*)&xt[r * XTS + 4 * g];
      cur.x -= tr4[k].x; cur.y -= tr4[k].y;
      cur.z -= tr4[k].z; cur.w -= tr4[k].w;
      *(float4*)&xt[r * XTS + 4 * g] = cur;
    }
  }
  __syncthreads();     // barrier 3

  // TV Dy term on d: |d(r,c) - d(r+1,c)|, r < HH-1
  {
    int gc = ox + ln;
    if (gc < W) {
      #pragma unroll
      for (int i = 0; i < RW; ++i) {
        int r = r0 + i;
        if (oy + r < HH - 1)
          tvl += fabsf(xt[r * XTS + ln] - xt[(r + 1) * XTS + ln]);
      }
    }
  }

  // term 2: conv(d, Gyy) = vert a, horiz bb
  VPASS(tp.a);
  HSECOND(tp.bb, 1.0f);

  // term 3: conv(d, Gxy) = vert m, horiz n, weight 2 (isotropic)
  VPASS(tp.m);
  HSECOND(tp.n, 2.0f);

  // folded gf term (gf(x,x)==x exactly -> sum|st-x|) + sampled L1*map;
  // operands loaded before barrier 1, latency hidden under the conv.
  float gm = fabsf(gb0.x - ga0.x) + fabsf(gb0.y - ga0.y)
           + fabsf(gb0.z - ga0.z) + fabsf(gb0.w - ga0.w);
  if (has1)
    gm += fabsf(gb1.x - ga1.x) + fabsf(gb1.y - ga1.y)
        + fabsf(gb1.z - ga1.z) + fabsf(gb1.w - ga1.w);
  if (hasm) gm += fabsf(mT - mG) * mM;

  // ---- fused block reduction: one barrier, 3 slot atomics by thread 0 ----
  #pragma unroll
  for (int o = 32; o > 0; o >>= 1) {
    gm  += __shfl_down(gm,  o, 64);
    tvl += __shfl_down(tvl, o, 64);
    hl  += __shfl_down(hl,  o, 64);
  }
  if (ln == 0) { red[wv][0] = gm; red[wv][1] = tvl; red[wv][2] = hl; }
  __syncthreads();     // barrier 4 (final)
  if (t == 0) {
    int slot = bid & (NSLOT - 1);
    double* base = g_slots + (size_t)slot * 32;
    unsafeAtomicAdd(base,      (double)(red[0][0] + red[1][0] + red[2][0] + red[3][0]));
    unsafeAtomicAdd(base + 8,  (double)(red[0][1] + red[1][1] + red[2][1] + red[3][1]));
    unsafeAtomicAdd(base + 16, (double)(red[0][2] + red[1][2] + red[2][2] + red[3][2]));
    __threadfence();   // slot atomics reach the coherent point before ticket
    unsigned int tk = atomicAdd(&g_ticket, 1);
    lastflag = (tk == NBLK - 1) ? 1u : 0u;
  }
  __syncthreads();

  // ---- last block: coherent read + re-zero of all slots (atomicExch goes
  // through the same memory-side path as the adds), reduce, write result.
  if (lastflag) {
    if (t == 0) g_ticket = 0;    // self-reset for the next launch/replay
    if (t < 64) {                // wave 0 only: lane s owns slot s
      unsigned long long* b = (unsigned long long*)(g_slots + (size_t)t * 32);
      double s0 = __longlong_as_double(atomicExch(b,      0ull));
      double s1 = __longlong_as_double(atomicExch(b + 8,  0ull));
      double s3 = __longlong_as_double(atomicExch(b + 16, 0ull));
      #pragma unroll
      for (int o = 32; o > 0; o >>= 1) {
        s0 += __shfl_down(s0, o, 64);
        s1 += __shfl_down(s1, o, 64);
        s3 += __shfl_down(s3, o, 64);
      }
      if (t == 0) out[0] = (float)(s0 + 0.1 * s1 + 0.5 * s3);
    }
  }
}

extern "C" void kernel_launch(void* const* d_in, const int* in_sizes, int n_in,
                              void* d_out, int out_size, void* d_ws, size_t ws_size,
                              hipStream_t stream) {
  const float* xraw = (const float*)d_in[0];   // outputGNNraw
  const float* gnn  = (const float*)d_in[1];   // outputGNN
  const float* lr   = (const float*)d_in[2];   // outputLR
  const float* st   = (const float*)d_in[3];   // smoothedTarget
  const float* tg   = (const float*)d_in[4];   // targets
  const float* mp   = (const float*)d_in[5];   // map
  float* out = (float*)d_out;

  // separable Hessian-of-Gaussian taps (sigma=1, t = -6..6):
  //   Gxx[i,j] = bb(i)*a(j); Gyy[i,j] = a(i)*bb(j); Gxy[i,j] = m(i)*n(j)
  HessTaps tp;
  const double PI2 = 6.283185307179586476925287;
  for (int k = 0; k < 13; ++k) {
    double tt = (double)(k - 6);
    double g = exp(-0.5 * tt * tt);
    tp.a[k]  = (float)((tt * tt - 1.0) * g / PI2);
    tp.bb[k] = (float)g;
    tp.m[k]  = (float)(tt * g / PI2);
    tp.n[k]  = (float)(tt * g);
  }

  // ONE dispatch: grid 48 x-tiles * 70 y-tiles (70*44=3080 >= 3072, masked)
  // * {GNN, LR}; accumulator state lives in self-resetting module globals.
  hess_kernel<<<dim3(GX, GY, GZ), 256, 0, stream>>>(gnn, lr, tg, xraw, st, mp,
                                                    out, tp);
}

// Round 8
// 402.709 us; speedup vs baseline: 1.0002x; 1.0002x over previous
//
#include <hip/hip_runtime.h>
#include <math.h>

#define W    3072
#define HH   3072
#define HOUT 3060       // HH - 12 (valid conv output for 13x13 kernel)
#define TW   64         // output cols per block
#define TH   44         // output rows per block (4 waves x 11 rows)
#define RW   11         // rows per wave
#define XR   56         // xt rows = TH + 12
#define XTS  76         // xt col stride
#define VTS  77         // vt col stride (odd -> scalar reads/writes conflict-free)
#define VTW  (RW*VTS)   // per-wave vt words = 847
#define GX   48
#define GY   70         // 70*44 = 3080 >= 3072 (masked)
#define GZ   2
#define NBLK (GX*GY*GZ)
#define NTHR (NBLK*256)
#define NSLOT 64        // accumulator slots, each (slot,j) on its own 64B line
#define QUOTA (NBLK/NSLOT)       // 6720/64 = 105 blocks per slot (exact)
#define NSTG ((XR*19+255)/256)   // staging iterations per thread = 5

struct HessTaps { float a[13]; float bb[13]; float m[13]; float n[13]; };

// ---- module-global accumulator state: zero-init at load, SELF-RESETTING.
// LESSON (rounds 0-4, re-learned round 7): atomics to one 64B line serialize
// at ~13ns AND blocks hold CU residency while waiting on the atomic return,
// throttling the whole grid. Round 7's single g_ticket (6720 same-line RMWs)
// cost +153us. Fix: HIERARCHICAL completion count -- per-slot tickets on
// separate lines (105 atomics/line) feeding one 64-atomic level-2 line.
__device__ double       g_slots[NSLOT * 32];   // (slot,j) at byte slot*256+j*64
__device__ unsigned int g_tick1[NSLOT * 16];   // per-slot ticket, own 64B line
__device__ unsigned int g_tick2 = 0;           // level-2: only 64 arrivals

// ---- Hessian + TV + folded gf/mse, both images via gridDim.z ---------------
// 64x44 output tile, 4 waves x 11 rows, wave-local V->H (vt wave-private),
// scalar f32 FMAs (v_pk_fma_f32 is half-rate on gfx950: fp32 peak == scalar
// FMA rate, verified rounds 1-2). Conv body identical to round 6 (117us,
// VALUBusy 72%, occupancy 49% @ 5 blocks/CU):
//  * TH 44 -> LDS 30628 -> 5 blocks/CU (occupancy ceiling 62.5%).
//  * T window preloaded into 5 static float4 regs BEFORE barrier 1: the
//    d-update phase is pure LDS/VALU (no global-load bubble).
//  * gf/mse global loads issued before barrier 1, consumed at the end.
// Single dispatch: fused end reduction + hierarchical-ticket finalize.
__global__ __launch_bounds__(256, 5) void hess_kernel(const float* __restrict__ Gnn,
                                                      const float* __restrict__ Lr,
                                                      const float* __restrict__ T,
                                                      const float* __restrict__ Xr,
                                                      const float* __restrict__ St,
                                                      const float* __restrict__ Mp,
                                                      float* __restrict__ out,
                                                      HessTaps tp) {
  __shared__ float xt[XR * XTS];
  __shared__ float vt[4 * VTW];
  __shared__ float red[4][3];
  __shared__ unsigned int lastflag;
  const float* img = (blockIdx.z == 0) ? Gnn : Lr;
  int oy = blockIdx.y * TH, ox = blockIdx.x * TW;
  int t = threadIdx.x;
  int wv = t >> 6, ln = t & 63;    // wave id 0..3, lane 0..63
  int r0 = wv * RW;

  // load xt (56 rows x 76 cols) as aligned float4 with edge masking
  for (int idx = t; idx < XR * 19; idx += 256) {
    int r = idx / 19, g = idx - r * 19;
    int gr = oy + r, gc = ox + 4 * g;
    float4 v = {0.f, 0.f, 0.f, 0.f};
    if (gr < HH) {
      const float* p = &img[(size_t)gr * W + gc];
      if (gc + 3 < W) v = *(const float4*)p;
      else {
        if (gc < W)     v.x = p[0];
        if (gc + 1 < W) v.y = p[1];
        if (gc + 2 < W) v.z = p[2];
      }
    }
    *(float4*)&xt[r * XTS + 4 * g] = v;
  }

  // ---- preload the T window for the d-update (static 5x float4, masked);
  // latency hides under term-1 compute instead of stalling at barrier 2.
  float4 tr4[NSTG];
  #pragma unroll
  for (int k = 0; k < NSTG; ++k) {
    int idx = t + 256 * k;
    float4 v = {0.f, 0.f, 0.f, 0.f};
    if (idx < XR * 19) {
      int r = idx / 19, g = idx - r * 19;
      int gr = oy + r, gc = ox + 4 * g;
      if (gr < HH) {
        const float* p = &T[(size_t)gr * W + gc];
        if (gc + 3 < W) v = *(const float4*)p;
        else {
          if (gc < W)     v.x = p[0];
          if (gc + 1 < W) v.y = p[1];
          if (gc + 2 < W) v.z = p[2];
        }
      }
    }
    tr4[k] = v;
  }

  // ---- issue gf/mse global loads now; latency hides under the whole conv
  int bid = (blockIdx.z * GY + blockIdx.y) * GX + blockIdx.x;
  int i0 = bid * 256 + t;
  int i1 = i0 + NTHR;
  const int n4 = (W * HH) / 4;
  float4 ga0 = ((const float4*)Xr)[i0];    // i0 < NTHR <= n4 always
  float4 gb0 = ((const float4*)St)[i0];
  float4 ga1 = {0.f, 0.f, 0.f, 0.f}, gb1 = ga1;
  bool has1 = (i1 < n4);
  if (has1) { ga1 = ((const float4*)Xr)[i1]; gb1 = ((const float4*)St)[i1]; }
  float mT = 0.f, mG = 0.f, mM = 0.f;
  bool hasm = (i0 < 384 * 384);
  if (hasm) {
    int si = i0 / 384, sj = i0 - si * 384;
    int id = si * 8 * W + sj * 8;
    mT = T[id]; mG = Gnn[id]; mM = Mp[id];
  }
  __builtin_amdgcn_sched_barrier(0);

  __syncthreads();     // barrier 1: xt staged

  float tvl = 0.f;   // TV accumulator
  float hl  = 0.f;   // Hessian accumulator

  // TV Dx term on x: |x(r,c) - x(r,c+1)|  (lanes contiguous -> free)
  {
    int gc = ox + ln;
    if (gc < W - 1) {
      #pragma unroll
      for (int i = 0; i < RW; ++i) {
        int r = r0 + i;
        if (oy + r < HH)
          tvl += fabsf(xt[r * XTS + ln] - xt[r * XTS + ln + 1]);
      }
    }
  }

  // ---- V pass: main 64 cols (all lanes) + dense halo (12x11=132 outputs,
  // <=3 per lane). Per-output tap order u-ascending -> bitwise identical.
  #define VPASS(TAP)                                                        \
    {                                                                       \
      /* main: lane = col ln; 11 sliding accumulators over 23-row window */ \
      float oA[RW];                                                         \
      _Pragma("unroll")                                                     \
      for (int i = 0; i < RW; ++i) oA[i] = 0.f;                             \
      _Pragma("unroll")                                                     \
      for (int u = 0; u < RW + 12; ++u) {                                   \
        float xA = xt[(r0 + u) * XTS + ln];                                 \
        _Pragma("unroll")                                                   \
        for (int i = 0; i < RW; ++i) {                                      \
          int kk = u - i;                                                   \
          if (kk >= 0 && kk <= 12) oA[i] = fmaf((TAP)[kk], xA, oA[i]);      \
        }                                                                   \
      }                                                                     \
      float* vw = &vt[wv * VTW + ln];                                       \
      _Pragma("unroll")                                                     \
      for (int i = 0; i < RW; ++i) vw[i * VTS] = oA[i];                     \
      /* halo: 12 cols x 11 rows = 132 outputs, <=3 per lane */             \
      _Pragma("unroll")                                                     \
      for (int k = 0; k < 3; ++k) {                                         \
        int o = ln + 64 * k;                                                \
        if (o < 12 * RW) {                                                  \
          int row = o / 12, hc = o - row * 12;                              \
          const float* xp = &xt[(r0 + row) * XTS + 64 + hc];                \
          float s = 0.f;                                                    \
          _Pragma("unroll")                                                 \
          for (int u = 0; u < 13; ++u) s = fmaf((TAP)[u], xp[u * XTS], s);  \
          vt[wv * VTW + row * VTS + 64 + hc] = s;                           \
        }                                                                   \
      }                                                                     \
    }

  // ---- H pass: scalar sliding reads of the SAME wave's vt rows (stride 77
  // -> <=2 lanes/bank); 16 register accumulators, tap order j-ascending.
  #define HSECOND(TAP, WGT)                                                 \
    {                                                                       \
      int r14 = ln & 15, cg = ln >> 4;                                      \
      if (r14 < RW) {                                                       \
        const float* vrow = &vt[wv * VTW + r14 * VTS + cg * 16];            \
        float o_[16];                                                       \
        _Pragma("unroll")                                                   \
        for (int jj = 0; jj < 16; ++jj) o_[jj] = 0.f;                       \
        _Pragma("unroll")                                                   \
        for (int j = 0; j < 28; ++j) {                                      \
          float v = vrow[j];                                                \
          _Pragma("unroll")                                                 \
          for (int jj = 0; jj < 16; ++jj) {                                 \
            int kk = j - jj;                                                \
            if (kk >= 0 && kk <= 12) o_[jj] = fmaf((TAP)[kk], v, o_[jj]);   \
          }                                                                 \
        }                                                                   \
        int gr = oy + r0 + r14;                                             \
        int gc0 = ox + cg * 16;                                             \
        float wr = (gr < HOUT) ? (WGT) : 0.f;                               \
        _Pragma("unroll")                                                   \
        for (int jj = 0; jj < 16; ++jj) {                                   \
          float m_ = (gc0 + jj < HOUT) ? wr : 0.f;                          \
          hl = fmaf(m_, fabsf(o_[jj]), hl);                                 \
        }                                                                   \
      }                                                                     \
    }

  // term 1: conv(x, Gxx) = vert bb, horiz a   (vt is wave-private: no barrier)
  VPASS(tp.bb);
  HSECOND(tp.a, 1.0f);

  // d = x - target (in place), using the preloaded T registers: pure
  // LDS/VALU between the barriers -- no global-load bubble.
  __syncthreads();     // barrier 2
  #pragma unroll
  for (int k = 0; k < NSTG; ++k) {
    int idx = t + 256 * k;
    if (idx < XR * 19) {
      int r = idx / 19, g = idx - r * 19;
      float4 cur = *(float4*)&xt[r * XTS + 4 * g];
      cur.x -= tr4[k].x; cur.y -= tr4[k].y;
      cur.z -= tr4[k].z; cur.w -= tr4[k].w;
      *(float4*)&xt[r * XTS + 4 * g] = cur;
    }
  }
  __syncthreads();     // barrier 3

  // TV Dy term on d: |d(r,c) - d(r+1,c)|, r < HH-1
  {
    int gc = ox + ln;
    if (gc < W) {
      #pragma unroll
      for (int i = 0; i < RW; ++i) {
        int r = r0 + i;
        if (oy + r < HH - 1)
          tvl += fabsf(xt[r * XTS + ln] - xt[(r + 1) * XTS + ln]);
      }
    }
  }

  // term 2: conv(d, Gyy) = vert a, horiz bb
  VPASS(tp.a);
  HSECOND(tp.bb, 1.0f);

  // term 3: conv(d, Gxy) = vert m, horiz n, weight 2 (isotropic)
  VPASS(tp.m);
  HSECOND(tp.n, 2.0f);

  // folded gf term (gf(x,x)==x exactly -> sum|st-x|) + sampled L1*map;
  // operands loaded before barrier 1, latency hidden under the conv.
  float gm = fabsf(gb0.x - ga0.x) + fabsf(gb0.y - ga0.y)
           + fabsf(gb0.z - ga0.z) + fabsf(gb0.w - ga0.w);
  if (has1)
    gm += fabsf(gb1.x - ga1.x) + fabsf(gb1.y - ga1.y)
        + fabsf(gb1.z - ga1.z) + fabsf(gb1.w - ga1.w);
  if (hasm) gm += fabsf(mT - mG) * mM;

  // ---- fused block reduction: one barrier, 3 slot atomics by thread 0 ----
  #pragma unroll
  for (int o = 32; o > 0; o >>= 1) {
    gm  += __shfl_down(gm,  o, 64);
    tvl += __shfl_down(tvl, o, 64);
    hl  += __shfl_down(hl,  o, 64);
  }
  if (ln == 0) { red[wv][0] = gm; red[wv][1] = tvl; red[wv][2] = hl; }
  __syncthreads();     // barrier 4 (final)
  if (t == 0) {
    int slot = bid & (NSLOT - 1);
    double* base = g_slots + (size_t)slot * 32;
    unsafeAtomicAdd(base,      (double)(red[0][0] + red[1][0] + red[2][0] + red[3][0]));
    unsafeAtomicAdd(base + 8,  (double)(red[0][1] + red[1][1] + red[2][1] + red[3][1]));
    unsafeAtomicAdd(base + 16, (double)(red[0][2] + red[1][2] + red[2][2] + red[3][2]));
    __threadfence();   // slot adds reach the coherent point before ticketing
    unsigned int last = 0;
    unsigned int tk = atomicAdd(&g_tick1[slot * 16], 1);   // 105 atomics/line
    if (tk == QUOTA - 1) {
      // this slot fully accumulated -> level-2 (only 64 arrivals total)
      unsigned int l2 = atomicAdd(&g_tick2, 1);
      last = (l2 == NSLOT - 1) ? 1u : 0u;
    }
    lastflag = last;
  }
  __syncthreads();

  // ---- last arrival: coherent read + re-zero of all state (atomicExch goes
  // through the same memory-side path as the adds), reduce, write result.
  if (lastflag) {
    if (t == 0) g_tick2 = 0;     // self-reset for the next launch/replay
    if (t < 64) {                // wave 0 only: lane s owns slot s
      g_tick1[t * 16] = 0;       // no other block active: plain store is safe
      unsigned long long* b = (unsigned long long*)(g_slots + (size_t)t * 32);
      double s0 = __longlong_as_double(atomicExch(b,      0ull));
      double s1 = __longlong_as_double(atomicExch(b + 8,  0ull));
      double s3 = __longlong_as_double(atomicExch(b + 16, 0ull));
      #pragma unroll
      for (int o = 32; o > 0; o >>= 1) {
        s0 += __shfl_down(s0, o, 64);
        s1 += __shfl_down(s1, o, 64);
        s3 += __shfl_down(s3, o, 64);
      }
      if (t == 0) out[0] = (float)(s0 + 0.1 * s1 + 0.5 * s3);
    }
  }
}

extern "C" void kernel_launch(void* const* d_in, const int* in_sizes, int n_in,
                              void* d_out, int out_size, void* d_ws, size_t ws_size,
                              hipStream_t stream) {
  const float* xraw = (const float*)d_in[0];   // outputGNNraw
  const float* gnn  = (const float*)d_in[1];   // outputGNN
  const float* lr   = (const float*)d_in[2];   // outputLR
  const float* st   = (const float*)d_in[3];   // smoothedTarget
  const float* tg   = (const float*)d_in[4];   // targets
  const float* mp   = (const float*)d_in[5];   // map
  float* out = (float*)d_out;

  // separable Hessian-of-Gaussian taps (sigma=1, t = -6..6):
  //   Gxx[i,j] = bb(i)*a(j); Gyy[i,j] = a(i)*bb(j); Gxy[i,j] = m(i)*n(j)
  HessTaps tp;
  const double PI2 = 6.283185307179586476925287;
  for (int k = 0; k < 13; ++k) {
    double tt = (double)(k - 6);
    double g = exp(-0.5 * tt * tt);
    tp.a[k]  = (float)((tt * tt - 1.0) * g / PI2);
    tp.bb[k] = (float)g;
    tp.m[k]  = (float)(tt * g / PI2);
    tp.n[k]  = (float)(tt * g);
  }

  // ONE dispatch: grid 48 x-tiles * 70 y-tiles (70*44=3080 >= 3072, masked)
  // * {GNN, LR}; accumulator state lives in self-resetting module globals.
  hess_kernel<<<dim3(GX, GY, GZ), 256, 0, stream>>>(gnn, lr, tg, xraw, st, mp,
                                                    out, tp);
}

// Round 9
// 260.096 us; speedup vs baseline: 1.5487x; 1.5483x over previous
//
#include <hip/hip_runtime.h>
#include <math.h>

#define W    3072
#define HH   3072
#define HOUT 3060       // HH - 12 (valid conv output for 13x13 kernel)
#define TW   64         // output cols per block
#define TH   44         // output rows per block (4 waves x 11 rows)
#define RW   11         // rows per wave
#define XR   56         // xt rows = TH + 12
#define XTS  76         // xt col stride
#define VTS  77         // vt col stride (odd -> scalar reads/writes conflict-free)
#define VTW  (RW*VTS)   // per-wave vt words = 847
#define GX   48
#define GY   70         // 70*44 = 3080 >= 3072 (masked)
#define GZ   2
#define NBLK (GX*GY*GZ)
#define NTHR (NBLK*256)
#define NSLOT 64        // accumulator slots, each (slot,j) on its own 64B line
#define NSTG ((XR*19+255)/256)   // staging iterations per thread = 5

struct HessTaps { float a[13]; float bb[13]; float m[13]; float n[13]; };

// ---- module-global accumulator state: zero-init at load, SELF-RESETTING
// (finalize re-zeroes after reading), so no memset dispatch is needed.
// LESSONS:
//  * rounds 0-4: atomics to ONE 64B line serialize (~13ns each) -> slot-spread
//    across 64 lines (round 5: 798 -> 123us).
//  * rounds 7-8: an IN-KERNEL completion protocol (threadfence + returning
//    ticket atomic + final barrier) costs ~150us: every block's 4 waves hold
//    their CU residency slot through a cache-maintenance fence + atomic round
//    trip (ticket-line spreading changed nothing -> contention falsified; the
//    per-block tail itself is the cost). Fix: NO in-kernel protocol at all --
//    kernel-boundary stream ordering provides release/acquire for free.
__device__ double g_slots[NSLOT * 32];   // (slot,j) at byte slot*256 + j*64

// ---- Hessian + TV + folded gf/mse, both images via gridDim.z ---------------
// 64x44 output tile, 4 waves x 11 rows, wave-local V->H (vt wave-private),
// scalar f32 FMAs (v_pk_fma_f32 is half-rate on gfx950: fp32 peak == scalar
// FMA rate, verified rounds 1-2). Conv body identical to round 6 (117us,
// VALUBusy 72%, occupancy 49% @ 5 blocks/CU):
//  * TH 44 -> LDS 30628 -> 5 blocks/CU (occupancy ceiling 62.5%).
//  * T window preloaded into 5 static float4 regs BEFORE barrier 1: the
//    d-update phase is pure LDS/VALU (no global-load bubble).
//  * gf/mse global loads issued before barrier 1, consumed at the end.
// Ends with: fused 1-barrier block reduction + 3 fire-and-forget slot atomics.
__global__ __launch_bounds__(256, 5) void hess_kernel(const float* __restrict__ Gnn,
                                                      const float* __restrict__ Lr,
                                                      const float* __restrict__ T,
                                                      const float* __restrict__ Xr,
                                                      const float* __restrict__ St,
                                                      const float* __restrict__ Mp,
                                                      HessTaps tp) {
  __shared__ float xt[XR * XTS];
  __shared__ float vt[4 * VTW];
  __shared__ float red[4][3];
  const float* img = (blockIdx.z == 0) ? Gnn : Lr;
  int oy = blockIdx.y * TH, ox = blockIdx.x * TW;
  int t = threadIdx.x;
  int wv = t >> 6, ln = t & 63;    // wave id 0..3, lane 0..63
  int r0 = wv * RW;

  // load xt (56 rows x 76 cols) as aligned float4 with edge masking
  for (int idx = t; idx < XR * 19; idx += 256) {
    int r = idx / 19, g = idx - r * 19;
    int gr = oy + r, gc = ox + 4 * g;
    float4 v = {0.f, 0.f, 0.f, 0.f};
    if (gr < HH) {
      const float* p = &img[(size_t)gr * W + gc];
      if (gc + 3 < W) v = *(const float4*)p;
      else {
        if (gc < W)     v.x = p[0];
        if (gc + 1 < W) v.y = p[1];
        if (gc + 2 < W) v.z = p[2];
      }
    }
    *(float4*)&xt[r * XTS + 4 * g] = v;
  }

  // ---- preload the T window for the d-update (static 5x float4, masked);
  // latency hides under term-1 compute instead of stalling at barrier 2.
  float4 tr4[NSTG];
  #pragma unroll
  for (int k = 0; k < NSTG; ++k) {
    int idx = t + 256 * k;
    float4 v = {0.f, 0.f, 0.f, 0.f};
    if (idx < XR * 19) {
      int r = idx / 19, g = idx - r * 19;
      int gr = oy + r, gc = ox + 4 * g;
      if (gr < HH) {
        const float* p = &T[(size_t)gr * W + gc];
        if (gc + 3 < W) v = *(const float4*)p;
        else {
          if (gc < W)     v.x = p[0];
          if (gc + 1 < W) v.y = p[1];
          if (gc + 2 < W) v.z = p[2];
        }
      }
    }
    tr4[k] = v;
  }

  // ---- issue gf/mse global loads now; latency hides under the whole conv
  int bid = (blockIdx.z * GY + blockIdx.y) * GX + blockIdx.x;
  int i0 = bid * 256 + t;
  int i1 = i0 + NTHR;
  const int n4 = (W * HH) / 4;
  float4 ga0 = ((const float4*)Xr)[i0];    // i0 < NTHR <= n4 always
  float4 gb0 = ((const float4*)St)[i0];
  float4 ga1 = {0.f, 0.f, 0.f, 0.f}, gb1 = ga1;
  bool has1 = (i1 < n4);
  if (has1) { ga1 = ((const float4*)Xr)[i1]; gb1 = ((const float4*)St)[i1]; }
  float mT = 0.f, mG = 0.f, mM = 0.f;
  bool hasm = (i0 < 384 * 384);
  if (hasm) {
    int si = i0 / 384, sj = i0 - si * 384;
    int id = si * 8 * W + sj * 8;
    mT = T[id]; mG = Gnn[id]; mM = Mp[id];
  }
  __builtin_amdgcn_sched_barrier(0);

  __syncthreads();     // barrier 1: xt staged

  float tvl = 0.f;   // TV accumulator
  float hl  = 0.f;   // Hessian accumulator

  // TV Dx term on x: |x(r,c) - x(r,c+1)|  (lanes contiguous -> free)
  {
    int gc = ox + ln;
    if (gc < W - 1) {
      #pragma unroll
      for (int i = 0; i < RW; ++i) {
        int r = r0 + i;
        if (oy + r < HH)
          tvl += fabsf(xt[r * XTS + ln] - xt[r * XTS + ln + 1]);
      }
    }
  }

  // ---- V pass: main 64 cols (all lanes) + dense halo (12x11=132 outputs,
  // <=3 per lane). Per-output tap order u-ascending -> bitwise identical.
  #define VPASS(TAP)                                                        \
    {                                                                       \
      /* main: lane = col ln; 11 sliding accumulators over 23-row window */ \
      float oA[RW];                                                         \
      _Pragma("unroll")                                                     \
      for (int i = 0; i < RW; ++i) oA[i] = 0.f;                             \
      _Pragma("unroll")                                                     \
      for (int u = 0; u < RW + 12; ++u) {                                   \
        float xA = xt[(r0 + u) * XTS + ln];                                 \
        _Pragma("unroll")                                                   \
        for (int i = 0; i < RW; ++i) {                                      \
          int kk = u - i;                                                   \
          if (kk >= 0 && kk <= 12) oA[i] = fmaf((TAP)[kk], xA, oA[i]);      \
        }                                                                   \
      }                                                                     \
      float* vw = &vt[wv * VTW + ln];                                       \
      _Pragma("unroll")                                                     \
      for (int i = 0; i < RW; ++i) vw[i * VTS] = oA[i];                     \
      /* halo: 12 cols x 11 rows = 132 outputs, <=3 per lane */             \
      _Pragma("unroll")                                                     \
      for (int k = 0; k < 3; ++k) {                                         \
        int o = ln + 64 * k;                                                \
        if (o < 12 * RW) {                                                  \
          int row = o / 12, hc = o - row * 12;                              \
          const float* xp = &xt[(r0 + row) * XTS + 64 + hc];                \
          float s = 0.f;                                                    \
          _Pragma("unroll")                                                 \
          for (int u = 0; u < 13; ++u) s = fmaf((TAP)[u], xp[u * XTS], s);  \
          vt[wv * VTW + row * VTS + 64 + hc] = s;                           \
        }                                                                   \
      }                                                                     \
    }

  // ---- H pass: scalar sliding reads of the SAME wave's vt rows (stride 77
  // -> <=2 lanes/bank); 16 register accumulators, tap order j-ascending.
  #define HSECOND(TAP, WGT)                                                 \
    {                                                                       \
      int r14 = ln & 15, cg = ln >> 4;                                      \
      if (r14 < RW) {                                                       \
        const float* vrow = &vt[wv * VTW + r14 * VTS + cg * 16];            \
        float o_[16];                                                       \
        _Pragma("unroll")                                                   \
        for (int jj = 0; jj < 16; ++jj) o_[jj] = 0.f;                       \
        _Pragma("unroll")                                                   \
        for (int j = 0; j < 28; ++j) {                                      \
          float v = vrow[j];                                                \
          _Pragma("unroll")                                                 \
          for (int jj = 0; jj < 16; ++jj) {                                 \
            int kk = j - jj;                                                \
            if (kk >= 0 && kk <= 12) o_[jj] = fmaf((TAP)[kk], v, o_[jj]);   \
          }                                                                 \
        }                                                                   \
        int gr = oy + r0 + r14;                                             \
        int gc0 = ox + cg * 16;                                             \
        float wr = (gr < HOUT) ? (WGT) : 0.f;                               \
        _Pragma("unroll")                                                   \
        for (int jj = 0; jj < 16; ++jj) {                                   \
          float m_ = (gc0 + jj < HOUT) ? wr : 0.f;                          \
          hl = fmaf(m_, fabsf(o_[jj]), hl);                                 \
        }                                                                   \
      }                                                                     \
    }

  // term 1: conv(x, Gxx) = vert bb, horiz a   (vt is wave-private: no barrier)
  VPASS(tp.bb);
  HSECOND(tp.a, 1.0f);

  // d = x - target (in place), using the preloaded T registers: pure
  // LDS/VALU between the barriers -- no global-load bubble.
  __syncthreads();     // barrier 2
  #pragma unroll
  for (int k = 0; k < NSTG; ++k) {
    int idx = t + 256 * k;
    if (idx < XR * 19) {
      int r = idx / 19, g = idx - r * 19;
      float4 cur = *(float4*)&xt[r * XTS + 4 * g];
      cur.x -= tr4[k].x; cur.y -= tr4[k].y;
      cur.z -= tr4[k].z; cur.w -= tr4[k].w;
      *(float4*)&xt[r * XTS + 4 * g] = cur;
    }
  }
  __syncthreads();     // barrier 3

  // TV Dy term on d: |d(r,c) - d(r+1,c)|, r < HH-1
  {
    int gc = ox + ln;
    if (gc < W) {
      #pragma unroll
      for (int i = 0; i < RW; ++i) {
        int r = r0 + i;
        if (oy + r < HH - 1)
          tvl += fabsf(xt[r * XTS + ln] - xt[(r + 1) * XTS + ln]);
      }
    }
  }

  // term 2: conv(d, Gyy) = vert a, horiz bb
  VPASS(tp.a);
  HSECOND(tp.bb, 1.0f);

  // term 3: conv(d, Gxy) = vert m, horiz n, weight 2 (isotropic)
  VPASS(tp.m);
  HSECOND(tp.n, 2.0f);

  // folded gf term (gf(x,x)==x exactly -> sum|st-x|) + sampled L1*map;
  // operands loaded before barrier 1, latency hidden under the conv.
  float gm = fabsf(gb0.x - ga0.x) + fabsf(gb0.y - ga0.y)
           + fabsf(gb0.z - ga0.z) + fabsf(gb0.w - ga0.w);
  if (has1)
    gm += fabsf(gb1.x - ga1.x) + fabsf(gb1.y - ga1.y)
        + fabsf(gb1.z - ga1.z) + fabsf(gb1.w - ga1.w);
  if (hasm) gm += fabsf(mT - mG) * mM;

  // ---- fused block reduction: one barrier, then 3 FIRE-AND-FORGET slot
  // atomics by thread 0 and IMMEDIATE exit (no fence, no ticket, no tail:
  // kernel-boundary ordering makes the adds visible to finalize_kernel).
  #pragma unroll
  for (int o = 32; o > 0; o >>= 1) {
    gm  += __shfl_down(gm,  o, 64);
    tvl += __shfl_down(tvl, o, 64);
    hl  += __shfl_down(hl,  o, 64);
  }
  if (ln == 0) { red[wv][0] = gm; red[wv][1] = tvl; red[wv][2] = hl; }
  __syncthreads();     // barrier 4 (final)
  if (t == 0) {
    int slot = bid & (NSLOT - 1);
    double* base = g_slots + (size_t)slot * 32;
    unsafeAtomicAdd(base,      (double)(red[0][0] + red[1][0] + red[2][0] + red[3][0]));
    unsafeAtomicAdd(base + 8,  (double)(red[0][1] + red[1][1] + red[2][1] + red[3][1]));
    unsafeAtomicAdd(base + 16, (double)(red[0][2] + red[1][2] + red[2][2] + red[3][2]));
  }
}

// ---- combine (1 wave): plain loads (kernel boundary = acquire), re-zero the
// slots for the next launch/replay (kernel end = release), write the result.
__global__ __launch_bounds__(64) void finalize_kernel(float* __restrict__ out) {
  int t = threadIdx.x;             // lane t owns slot t
  double* b = g_slots + (size_t)t * 32;
  double s0 = b[0];  b[0]  = 0.0;
  double s1 = b[8];  b[8]  = 0.0;
  double s3 = b[16]; b[16] = 0.0;
  #pragma unroll
  for (int o = 32; o > 0; o >>= 1) {
    s0 += __shfl_down(s0, o, 64);
    s1 += __shfl_down(s1, o, 64);
    s3 += __shfl_down(s3, o, 64);
  }
  if (t == 0) out[0] = (float)(s0 + 0.1 * s1 + 0.5 * s3);
}

extern "C" void kernel_launch(void* const* d_in, const int* in_sizes, int n_in,
                              void* d_out, int out_size, void* d_ws, size_t ws_size,
                              hipStream_t stream) {
  const float* xraw = (const float*)d_in[0];   // outputGNNraw
  const float* gnn  = (const float*)d_in[1];   // outputGNN
  const float* lr   = (const float*)d_in[2];   // outputLR
  const float* st   = (const float*)d_in[3];   // smoothedTarget
  const float* tg   = (const float*)d_in[4];   // targets
  const float* mp   = (const float*)d_in[5];   // map
  float* out = (float*)d_out;

  // separable Hessian-of-Gaussian taps (sigma=1, t = -6..6):
  //   Gxx[i,j] = bb(i)*a(j); Gyy[i,j] = a(i)*bb(j); Gxy[i,j] = m(i)*n(j)
  HessTaps tp;
  const double PI2 = 6.283185307179586476925287;
  for (int k = 0; k < 13; ++k) {
    double tt = (double)(k - 6);
    double g = exp(-0.5 * tt * tt);
    tp.a[k]  = (float)((tt * tt - 1.0) * g / PI2);
    tp.bb[k] = (float)g;
    tp.m[k]  = (float)(tt * g / PI2);
    tp.n[k]  = (float)(tt * g);
  }

  // TWO dispatches (no memset: globals are self-resetting):
  // grid 48 x-tiles * 70 y-tiles (70*44=3080 >= 3072, masked) * {GNN, LR}
  hess_kernel<<<dim3(GX, GY, GZ), 256, 0, stream>>>(gnn, lr, tg, xraw, st, mp,
                                                    tp);
  finalize_kernel<<<1, 64, 0, stream>>>(out);
}

// Round 10
// 249.435 us; speedup vs baseline: 1.6149x; 1.0427x over previous
//
#include <hip/hip_runtime.h>
#include <math.h>

#define W    3072
#define HH   3072
#define HOUT 3060       // HH - 12 (valid conv output for 13x13 kernel)
#define TW   64         // output cols per block
#define TH   36         // output rows per block (4 waves x 9 rows)
#define RW   9          // rows per wave
#define XR   48         // xt rows = TH + 12
#define XTS  76         // xt col stride
#define VTS  77         // vt col stride (odd -> V writes conflict-free, H ~3-way max)
#define VTW  (RW*VTS)   // per-wave vt words = 693
#define GX   48
#define GY   86         // 86*36 = 3096 >= 3072 (masked)
#define GZ   2
#define NBLK (GX*GY*GZ)
#define NTHR (NBLK*256)
#define NSLOT 64        // accumulator slots, each (slot,j) on its own 64B line
#define NSTG ((XR*19+255)/256)   // staging iterations per thread = 4

struct HessTaps { float a[13]; float bb[13]; float m[13]; float n[13]; };

// ---- module-global accumulator state: zero-init at load, SELF-RESETTING
// (finalize re-zeroes after reading), so no memset dispatch is needed.
// LESSONS:
//  * rounds 0-4: atomics to ONE 64B line serialize (~13ns each) -> slot-spread
//    across 64 lines (round 5: 798 -> 123us).
//  * rounds 7-8: ANY in-kernel completion protocol (threadfence + returning
//    ticket atomic + final barrier) costs ~150us of CU-residency hold time.
//    Kernel-boundary stream ordering is the free release/acquire (round 9).
__device__ double g_slots[NSLOT * 32];   // (slot,j) at byte slot*256 + j*64

// ---- Hessian + TV + folded gf/mse, both images via gridDim.z ---------------
// 64x36 output tile, 4 waves x 9 rows, wave-local V->H (vt wave-private),
// scalar f32 FMAs (v_pk_fma_f32 is half-rate on gfx950: fp32 peak == scalar
// FMA rate, verified rounds 1-2). Round-10 changes vs the 117us round-9 body:
//  * RW 11->9: LDS 25.8KB -> 6 blocks/CU (occupancy ceiling 62.5% -> 75%;
//    measured 49% @ 73% VALUBusy said latency/occupancy still binds).
//  * H pass remapped to 9 rows x 7 colgroups x 10 cols: 63/64 lanes useful
//    (was 44/64), 130 FMA slots/term vs 208 -> ~10% less issue per output.
//  * V halo now 2 iterations (108 outputs <= 128).
//  * T window preloaded into 4 static float4 regs BEFORE barrier 1; d-update
//    is pure LDS/VALU. gf/mse loads issued before barrier 1, consumed at end.
// LDS: xt 48*76*4=14592 + vt (4*693+16)*4=11152 + red 48 = 25792 -> 6 blk/CU.
__global__ __launch_bounds__(256, 6) void hess_kernel(const float* __restrict__ Gnn,
                                                      const float* __restrict__ Lr,
                                                      const float* __restrict__ T,
                                                      const float* __restrict__ Xr,
                                                      const float* __restrict__ St,
                                                      const float* __restrict__ Mp,
                                                      HessTaps tp) {
  __shared__ float xt[XR * XTS];
  __shared__ float vt[4 * VTW + 16];   // +16: cg=6 masked over-reads in-bounds
  __shared__ float red[4][3];
  const float* img = (blockIdx.z == 0) ? Gnn : Lr;
  int oy = blockIdx.y * TH, ox = blockIdx.x * TW;
  int t = threadIdx.x;
  int wv = t >> 6, ln = t & 63;    // wave id 0..3, lane 0..63
  int r0 = wv * RW;

  // load xt (48 rows x 76 cols) as aligned float4 with edge masking
  for (int idx = t; idx < XR * 19; idx += 256) {
    int r = idx / 19, g = idx - r * 19;
    int gr = oy + r, gc = ox + 4 * g;
    float4 v = {0.f, 0.f, 0.f, 0.f};
    if (gr < HH) {
      const float* p = &img[(size_t)gr * W + gc];
      if (gc + 3 < W) v = *(const float4*)p;
      else {
        if (gc < W)     v.x = p[0];
        if (gc + 1 < W) v.y = p[1];
        if (gc + 2 < W) v.z = p[2];
      }
    }
    *(float4*)&xt[r * XTS + 4 * g] = v;
  }

  // ---- preload the T window for the d-update (static 4x float4, masked);
  // latency hides under term-1 compute instead of stalling at barrier 2.
  float4 tr4[NSTG];
  #pragma unroll
  for (int k = 0; k < NSTG; ++k) {
    int idx = t + 256 * k;
    float4 v = {0.f, 0.f, 0.f, 0.f};
    if (idx < XR * 19) {
      int r = idx / 19, g = idx - r * 19;
      int gr = oy + r, gc = ox + 4 * g;
      if (gr < HH) {
        const float* p = &T[(size_t)gr * W + gc];
        if (gc + 3 < W) v = *(const float4*)p;
        else {
          if (gc < W)     v.x = p[0];
          if (gc + 1 < W) v.y = p[1];
          if (gc + 2 < W) v.z = p[2];
        }
      }
    }
    tr4[k] = v;
  }

  // ---- issue gf/mse global loads now; latency hides under the whole conv
  int bid = (blockIdx.z * GY + blockIdx.y) * GX + blockIdx.x;
  int i0 = bid * 256 + t;
  int i1 = i0 + NTHR;
  const int n4 = (W * HH) / 4;
  float4 ga0 = ((const float4*)Xr)[i0];    // i0 < NTHR <= n4 always
  float4 gb0 = ((const float4*)St)[i0];
  float4 ga1 = {0.f, 0.f, 0.f, 0.f}, gb1 = ga1;
  bool has1 = (i1 < n4);
  if (has1) { ga1 = ((const float4*)Xr)[i1]; gb1 = ((const float4*)St)[i1]; }
  float mT = 0.f, mG = 0.f, mM = 0.f;
  bool hasm = (i0 < 384 * 384);
  if (hasm) {
    int si = i0 / 384, sj = i0 - si * 384;
    int id = si * 8 * W + sj * 8;
    mT = T[id]; mG = Gnn[id]; mM = Mp[id];
  }
  __builtin_amdgcn_sched_barrier(0);

  __syncthreads();     // barrier 1: xt staged

  float tvl = 0.f;   // TV accumulator
  float hl  = 0.f;   // Hessian accumulator

  // TV Dx term on x: |x(r,c) - x(r,c+1)|  (lanes contiguous -> free)
  {
    int gc = ox + ln;
    if (gc < W - 1) {
      #pragma unroll
      for (int i = 0; i < RW; ++i) {
        int r = r0 + i;
        if (oy + r < HH)
          tvl += fabsf(xt[r * XTS + ln] - xt[r * XTS + ln + 1]);
      }
    }
  }

  // ---- V pass: main 64 cols (all lanes) + dense halo (12x9=108 outputs,
  // <=2 per lane). Per-output tap order u-ascending -> bitwise identical.
  #define VPASS(TAP)                                                        \
    {                                                                       \
      /* main: lane = col ln; 9 sliding accumulators over 21-row window */  \
      float oA[RW];                                                         \
      _Pragma("unroll")                                                     \
      for (int i = 0; i < RW; ++i) oA[i] = 0.f;                             \
      _Pragma("unroll")                                                     \
      for (int u = 0; u < RW + 12; ++u) {                                   \
        float xA = xt[(r0 + u) * XTS + ln];                                 \
        _Pragma("unroll")                                                   \
        for (int i = 0; i < RW; ++i) {                                      \
          int kk = u - i;                                                   \
          if (kk >= 0 && kk <= 12) oA[i] = fmaf((TAP)[kk], xA, oA[i]);      \
        }                                                                   \
      }                                                                     \
      float* vw = &vt[wv * VTW + ln];                                       \
      _Pragma("unroll")                                                     \
      for (int i = 0; i < RW; ++i) vw[i * VTS] = oA[i];                     \
      /* halo: 12 cols x 9 rows = 108 outputs, <=2 per lane */              \
      _Pragma("unroll")                                                     \
      for (int k = 0; k < 2; ++k) {                                         \
        int o = ln + 64 * k;                                                \
        if (o < 12 * RW) {                                                  \
          int row = o / 12, hc = o - row * 12;                              \
          const float* xp = &xt[(r0 + row) * XTS + 64 + hc];                \
          float s = 0.f;                                                    \
          _Pragma("unroll")                                                 \
          for (int u = 0; u < 13; ++u) s = fmaf((TAP)[u], xp[u * XTS], s);  \
          vt[wv * VTW + row * VTS + 64 + hc] = s;                           \
        }                                                                   \
      }                                                                     \
    }

  // ---- H pass: lane = (r9 = ln/7, cg = ln%7), 63/64 lanes useful; each
  // lane: 22 scalar sliding reads (<=3-way bank alias, cheap), 10 outputs
  // at cols cg*10..+9 (cg=6: jj>=4 masked; its over-reads hit vt's pad and
  // feed only masked outputs). Tap order j-ascending -> bitwise identical.
  #define HSECOND(TAP, WGT)                                                 \
    {                                                                       \
      int r9 = ln / 7, cg = ln - r9 * 7;                                    \
      if (ln < 63) {                                                        \
        const float* vrow = &vt[wv * VTW + r9 * VTS + cg * 10];             \
        float o_[10];                                                       \
        _Pragma("unroll")                                                   \
        for (int jj = 0; jj < 10; ++jj) o_[jj] = 0.f;                       \
        _Pragma("unroll")                                                   \
        for (int j = 0; j < 22; ++j) {                                      \
          float v = vrow[j];                                                \
          _Pragma("unroll")                                                 \
          for (int jj = 0; jj < 10; ++jj) {                                 \
            int kk = j - jj;                                                \
            if (kk >= 0 && kk <= 12) o_[jj] = fmaf((TAP)[kk], v, o_[jj]);   \
          }                                                                 \
        }                                                                   \
        int gr = oy + r0 + r9;                                              \
        int gc0 = ox + cg * 10;                                             \
        float wr = (gr < HOUT) ? (WGT) : 0.f;                               \
        _Pragma("unroll")                                                   \
        for (int jj = 0; jj < 10; ++jj) {                                   \
          int lc = cg * 10 + jj;                                            \
          float m_ = (lc < 64 && gc0 + jj < HOUT) ? wr : 0.f;               \
          hl = fmaf(m_, fabsf(o_[jj]), hl);                                 \
        }                                                                   \
      }                                                                     \
    }

  // term 1: conv(x, Gxx) = vert bb, horiz a   (vt is wave-private: no barrier)
  VPASS(tp.bb);
  HSECOND(tp.a, 1.0f);

  // d = x - target (in place), using the preloaded T registers: pure
  // LDS/VALU between the barriers -- no global-load bubble.
  __syncthreads();     // barrier 2
  #pragma unroll
  for (int k = 0; k < NSTG; ++k) {
    int idx = t + 256 * k;
    if (idx < XR * 19) {
      int r = idx / 19, g = idx - r * 19;
      float4 cur = *(float4*)&xt[r * XTS + 4 * g];
      cur.x -= tr4[k].x; cur.y -= tr4[k].y;
      cur.z -= tr4[k].z; cur.w -= tr4[k].w;
      *(float4*)&xt[r * XTS + 4 * g] = cur;
    }
  }
  __syncthreads();     // barrier 3

  // TV Dy term on d: |d(r,c) - d(r+1,c)|, r < HH-1
  {
    int gc = ox + ln;
    if (gc < W) {
      #pragma unroll
      for (int i = 0; i < RW; ++i) {
        int r = r0 + i;
        if (oy + r < HH - 1)
          tvl += fabsf(xt[r * XTS + ln] - xt[(r + 1) * XTS + ln]);
      }
    }
  }

  // term 2: conv(d, Gyy) = vert a, horiz bb
  VPASS(tp.a);
  HSECOND(tp.bb, 1.0f);

  // term 3: conv(d, Gxy) = vert m, horiz n, weight 2 (isotropic)
  VPASS(tp.m);
  HSECOND(tp.n, 2.0f);

  // folded gf term (gf(x,x)==x exactly -> sum|st-x|) + sampled L1*map;
  // operands loaded before barrier 1, latency hidden under the conv.
  float gm = fabsf(gb0.x - ga0.x) + fabsf(gb0.y - ga0.y)
           + fabsf(gb0.z - ga0.z) + fabsf(gb0.w - ga0.w);
  if (has1)
    gm += fabsf(gb1.x - ga1.x) + fabsf(gb1.y - ga1.y)
        + fabsf(gb1.z - ga1.z) + fabsf(gb1.w - ga1.w);
  if (hasm) gm += fabsf(mT - mG) * mM;

  // ---- fused block reduction: one barrier, then 3 FIRE-AND-FORGET slot
  // atomics by thread 0 and IMMEDIATE exit (no fence, no ticket, no tail).
  #pragma unroll
  for (int o = 32; o > 0; o >>= 1) {
    gm  += __shfl_down(gm,  o, 64);
    tvl += __shfl_down(tvl, o, 64);
    hl  += __shfl_down(hl,  o, 64);
  }
  if (ln == 0) { red[wv][0] = gm; red[wv][1] = tvl; red[wv][2] = hl; }
  __syncthreads();     // barrier 4 (final)
  if (t == 0) {
    int slot = bid & (NSLOT - 1);
    double* base = g_slots + (size_t)slot * 32;
    unsafeAtomicAdd(base,      (double)(red[0][0] + red[1][0] + red[2][0] + red[3][0]));
    unsafeAtomicAdd(base + 8,  (double)(red[0][1] + red[1][1] + red[2][1] + red[3][1]));
    unsafeAtomicAdd(base + 16, (double)(red[0][2] + red[1][2] + red[2][2] + red[3][2]));
  }
}

// ---- combine (1 wave): plain loads (kernel boundary = acquire), re-zero the
// slots for the next launch/replay (kernel end = release), write the result.
__global__ __launch_bounds__(64) void finalize_kernel(float* __restrict__ out) {
  int t = threadIdx.x;             // lane t owns slot t
  double* b = g_slots + (size_t)t * 32;
  double s0 = b[0];  b[0]  = 0.0;
  double s1 = b[8];  b[8]  = 0.0;
  double s3 = b[16]; b[16] = 0.0;
  #pragma unroll
  for (int o = 32; o > 0; o >>= 1) {
    s0 += __shfl_down(s0, o, 64);
    s1 += __shfl_down(s1, o, 64);
    s3 += __shfl_down(s3, o, 64);
  }
  if (t == 0) out[0] = (float)(s0 + 0.1 * s1 + 0.5 * s3);
}

extern "C" void kernel_launch(void* const* d_in, const int* in_sizes, int n_in,
                              void* d_out, int out_size, void* d_ws, size_t ws_size,
                              hipStream_t stream) {
  const float* xraw = (const float*)d_in[0];   // outputGNNraw
  const float* gnn  = (const float*)d_in[1];   // outputGNN
  const float* lr   = (const float*)d_in[2];   // outputLR
  const float* st   = (const float*)d_in[3];   // smoothedTarget
  const float* tg   = (const float*)d_in[4];   // targets
  const float* mp   = (const float*)d_in[5];   // map
  float* out = (float*)d_out;

  // separable Hessian-of-Gaussian taps (sigma=1, t = -6..6):
  //   Gxx[i,j] = bb(i)*a(j); Gyy[i,j] = a(i)*bb(j); Gxy[i,j] = m(i)*n(j)
  HessTaps tp;
  const double PI2 = 6.283185307179586476925287;
  for (int k = 0; k < 13; ++k) {
    double tt = (double)(k - 6);
    double g = exp(-0.5 * tt * tt);
    tp.a[k]  = (float)((tt * tt - 1.0) * g / PI2);
    tp.bb[k] = (float)g;
    tp.m[k]  = (float)(tt * g / PI2);
    tp.n[k]  = (float)(tt * g);
  }

  // TWO dispatches (no memset: globals are self-resetting):
  // grid 48 x-tiles * 86 y-tiles (86*36=3096 >= 3072, masked) * {GNN, LR}
  hess_kernel<<<dim3(GX, GY, GZ), 256, 0, stream>>>(gnn, lr, tg, xraw, st, mp,
                                                    tp);
  finalize_kernel<<<1, 64, 0, stream>>>(out);
}